// Round 1
// baseline (149.417 us; speedup 1.0000x reference)
//
#include <hip/hip_runtime.h>

#define NSAMP 65536
#define EMBED 256

// RX in stored (original) index coordinates.
// Partner of amp = idx ^ (KM<<6 | LM): KM = k-bit xor (register permute),
// LM = lane-bit xor (shfl_xor). RX is symmetric: new = c*mine - i*s*partner.
#define RX_GATE(KM, LM, CC, SS) do {                                          \
    float ux0 = sx[0 ^ (KM)], ux1 = sx[1 ^ (KM)];                             \
    float ux2 = sx[2 ^ (KM)], ux3 = sx[3 ^ (KM)];                             \
    float uy0 = sy[0 ^ (KM)], uy1 = sy[1 ^ (KM)];                             \
    float uy2 = sy[2 ^ (KM)], uy3 = sy[3 ^ (KM)];                             \
    if ((LM) != 0) {                                                          \
        ux0 = __shfl_xor(ux0, (LM), 64); uy0 = __shfl_xor(uy0, (LM), 64);     \
        ux1 = __shfl_xor(ux1, (LM), 64); uy1 = __shfl_xor(uy1, (LM), 64);     \
        ux2 = __shfl_xor(ux2, (LM), 64); uy2 = __shfl_xor(uy2, (LM), 64);     \
        ux3 = __shfl_xor(ux3, (LM), 64); uy3 = __shfl_xor(uy3, (LM), 64);     \
    }                                                                         \
    float nx0 = (CC)*sx[0] + (SS)*uy0, ny0 = (CC)*sy[0] - (SS)*ux0;           \
    float nx1 = (CC)*sx[1] + (SS)*uy1, ny1 = (CC)*sy[1] - (SS)*ux1;           \
    float nx2 = (CC)*sx[2] + (SS)*uy2, ny2 = (CC)*sy[2] - (SS)*ux2;           \
    float nx3 = (CC)*sx[3] + (SS)*uy3, ny3 = (CC)*sy[3] - (SS)*ux3;           \
    sx[0] = nx0; sy[0] = ny0; sx[1] = nx1; sy[1] = ny1;                       \
    sx[2] = nx2; sy[2] = ny2; sx[3] = nx3; sy[3] = ny3;                       \
} while (0)

#define BFLY(V) do {                                                          \
    V += __shfl_xor(V, 32, 64); V += __shfl_xor(V, 16, 64);                   \
    V += __shfl_xor(V, 8, 64);  V += __shfl_xor(V, 4, 64);                    \
    V += __shfl_xor(V, 2, 64);  V += __shfl_xor(V, 1, 64);                    \
} while (0)

__global__ __launch_bounds__(256) void ffq_kernel(
    const float* __restrict__ x,    // (65536, 256)
    const float* __restrict__ W1,   // (8, 256)
    const float* __restrict__ b1,   // (8,)
    const float* __restrict__ qw,   // (2, 8)
    const float* __restrict__ W2,   // (256, 8)
    const float* __restrict__ b2,   // (256,)
    float* __restrict__ out)        // (65536, 256)
{
    const int lane = threadIdx.x & 63;
    const int wid  = blockIdx.x * (blockDim.x >> 6) + (threadIdx.x >> 6);
    const int nw   = gridDim.x * (blockDim.x >> 6);

    // ---- hoisted per-lane constants (sample-invariant) ----
    float4 w1c[8];
#pragma unroll
    for (int q = 0; q < 8; ++q)
        w1c[q] = *(const float4*)(W1 + q * EMBED + 4 * lane);

    const float4 b2c = *(const float4*)(b2 + 4 * lane);
    float w2r[4][8];
#pragma unroll
    for (int j = 0; j < 4; ++j)
#pragma unroll
        for (int q = 0; q < 8; ++q)
            w2r[j][q] = W2[(4 * lane + j) * 8 + q];

    float qc[16], qs[16];
#pragma unroll
    for (int i = 0; i < 16; ++i) {
        float th = 0.5f * qw[i];
        qc[i] = __cosf(th);
        qs[i] = __sinf(th);
    }
    float b1h[8];
#pragma unroll
    for (int q = 0; q < 8; ++q) b1h[q] = 0.5f * b1[q];

    // measurement sign masks: rows of T = R^2 (final CNOT rings folded out)
    // zq uses T-row(bit 7-q); lane part below, k part is A/B/C pattern.
    const int lmask[8] = {0x15, 0x3F, 0x1F, 0x2F, 0x17, 0x2B, 0x15, 0x2A};
    float msign[8];
#pragma unroll
    for (int q = 0; q < 8; ++q)
        msign[q] = (__popc(lane & lmask[q]) & 1) ? -1.0f : 1.0f;

    const int wl = __popc(lane);   // popcount of lane-bit qubits

    for (int s = wid; s < NSAMP; s += nw) {
        // ---- h = x . W1^T + b1 (per-wave dot, butterfly reduce) ----
        const float4 xv = *(const float4*)(x + (size_t)s * EMBED + 4 * lane);
        float h[8];
#pragma unroll
        for (int q = 0; q < 8; ++q) {
            float v = xv.x * w1c[q].x + xv.y * w1c[q].y +
                      xv.z * w1c[q].z + xv.w * w1c[q].w;
            BFLY(v);
            h[q] = 0.5f * v + b1h[q];   // half-angle
        }

        float hc[8], hs[8];
#pragma unroll
        for (int q = 0; q < 8; ++q) { hc[q] = __cosf(h[q]); hs[q] = __sinf(h[q]); }

        // ---- direct product-state init: amp = prod(c/s) * (-i)^w ----
        // qubit q in 2..7 <-> lane bit (7-q); qubit 0,1 <-> k bits 1,0
        float m6 = 1.0f;
#pragma unroll
        for (int q = 2; q < 8; ++q) {
            const int bit = (lane >> (7 - q)) & 1;
            m6 *= bit ? hs[q] : hc[q];
        }
        const float kf0 = hc[0] * hc[1], kf1 = hc[0] * hs[1];
        const float kf2 = hs[0] * hc[1], kf3 = hs[0] * hs[1];

        float sx[4], sy[4];
#define PLACE(K, KF, KW) do {                                                 \
        const float r = m6 * (KF);                                            \
        const int w = (wl + (KW)) & 3;                                        \
        sx[K] = (w == 0) ? r : ((w == 2) ? -r : 0.0f);                        \
        sy[K] = (w == 1) ? -r : ((w == 3) ? r : 0.0f);                        \
} while (0)
        PLACE(0, kf0, 0);
        PLACE(1, kf1, 1);
        PLACE(2, kf2, 1);
        PLACE(3, kf3, 2);
#undef PLACE

        // ---- fixed layer 1 RX (identity coords): masks e_{7-q} ----
        RX_GATE(2, 0,  qc[0], qs[0]);
        RX_GATE(1, 0,  qc[1], qs[1]);
        RX_GATE(0, 32, qc[2], qs[2]);
        RX_GATE(0, 16, qc[3], qs[3]);
        RX_GATE(0, 8,  qc[4], qs[4]);
        RX_GATE(0, 4,  qc[5], qs[5]);
        RX_GATE(0, 2,  qc[6], qs[6]);
        RX_GATE(0, 1,  qc[7], qs[7]);

        // ---- fixed layer 2 RX: partner masks R^-1(e_{7-q}) ----
        RX_GATE(3, 0,  qc[8],  qs[8]);   // 0xC0
        RX_GATE(1, 32, qc[9],  qs[9]);   // 0x60
        RX_GATE(0, 48, qc[10], qs[10]);  // 0x30
        RX_GATE(0, 24, qc[11], qs[11]);  // 0x18
        RX_GATE(0, 12, qc[12], qs[12]);  // 0x0C
        RX_GATE(0, 6,  qc[13], qs[13]);  // 0x06
        RX_GATE(0, 3,  qc[14], qs[14]);  // 0x03
        RX_GATE(3, 1,  qc[15], qs[15]);  // 0xC1

        // ---- measurement: z_q = sum p(idx) * (-1)^parity(idx & Trow) ----
        const float p0 = sx[0]*sx[0] + sy[0]*sy[0];
        const float p1 = sx[1]*sx[1] + sy[1]*sy[1];
        const float p2 = sx[2]*sx[2] + sy[2]*sy[2];
        const float p3 = sx[3]*sx[3] + sy[3]*sy[3];
        const float Ap = (p0 + p2) - (p1 + p3);   // k-bit0 parity
        const float Bp = (p0 + p3) - (p1 + p2);   // k both-bits parity
        const float Cp = (p0 + p1) - (p2 + p3);   // k-bit1 parity

        float zv[8];
        zv[0] = msign[0] * Bp;
        zv[1] = msign[1] * Cp;
        zv[2] = msign[2] * Ap;
        zv[3] = msign[3] * Cp;
        zv[4] = msign[4] * Ap;
        zv[5] = msign[5] * Cp;
        zv[6] = msign[6] * Ap;
        zv[7] = msign[7] * Cp;
#pragma unroll
        for (int q = 0; q < 8; ++q) BFLY(zv[q]);

        // ---- out = z . W2^T + b2 ----
        float o0 = b2c.x, o1 = b2c.y, o2 = b2c.z, o3 = b2c.w;
#pragma unroll
        for (int q = 0; q < 8; ++q) {
            o0 += zv[q] * w2r[0][q];
            o1 += zv[q] * w2r[1][q];
            o2 += zv[q] * w2r[2][q];
            o3 += zv[q] * w2r[3][q];
        }
        *(float4*)(out + (size_t)s * EMBED + 4 * lane) = make_float4(o0, o1, o2, o3);
    }
}

extern "C" void kernel_launch(void* const* d_in, const int* in_sizes, int n_in,
                              void* d_out, int out_size, void* d_ws, size_t ws_size,
                              hipStream_t stream) {
    const float* x  = (const float*)d_in[0];
    const float* W1 = (const float*)d_in[1];
    const float* b1 = (const float*)d_in[2];
    const float* qw = (const float*)d_in[3];
    const float* W2 = (const float*)d_in[4];
    const float* b2 = (const float*)d_in[5];
    float* out = (float*)d_out;

    dim3 grid(2048), block(256);   // 8192 waves, 8 samples per wave
    hipLaunchKernelGGL(ffq_kernel, grid, block, 0, stream,
                       x, W1, b1, qw, W2, b2, out);
}